// Round 1
// 2236.910 us; speedup vs baseline: 1.1334x; 1.1334x over previous
//
#include <hip/hip_runtime.h>
#include <cstdint>
#include <cstddef>

#define BB 128    // batch
#define TT 80     // seq
#define EE 100    // emb dim
#define EP 128    // padded emb dim
#define UU 2048   // units
#define G3 6144   // 3*UU
#define PLANE (BB * UU)   // 262144 elements, one gate pre-activation plane

typedef __bf16 bf16x8 __attribute__((ext_vector_type(8)));
typedef float f32x4 __attribute__((ext_vector_type(4)));
typedef int   i32x4 __attribute__((ext_vector_type(4)));

static __device__ __forceinline__ unsigned short f2bf(float x) {
  union { float f; unsigned int u; } a; a.f = x;
  unsigned int r = a.u + 0x7fffu + ((a.u >> 16) & 1u);  // RNE
  return (unsigned short)(r >> 16);
}

static __device__ __forceinline__ float sigf(float x) {
  return 1.f / (1.f + __expf(-x));
}
static __device__ __forceinline__ float tanhfast(float x) {
  return 1.f - 2.f / (__expf(2.f * x) + 1.f);
}

// accumulate 8 bf16 plane values (one int4 load) into float[8]
static __device__ __forceinline__ void acc8(float* s, const unsigned short* p) {
  int4 v = *reinterpret_cast<const int4*>(p);
  unsigned int w0 = (unsigned int)v.x, w1 = (unsigned int)v.y,
               w2 = (unsigned int)v.z, w3 = (unsigned int)v.w;
  union { unsigned int u; float f; } c;
  c.u = w0 << 16;         s[0] += c.f;
  c.u = w0 & 0xffff0000u; s[1] += c.f;
  c.u = w1 << 16;         s[2] += c.f;
  c.u = w1 & 0xffff0000u; s[3] += c.f;
  c.u = w2 << 16;         s[4] += c.f;
  c.u = w2 & 0xffff0000u; s[5] += c.f;
  c.u = w3 << 16;         s[6] += c.f;
  c.u = w3 & 0xffff0000u; s[7] += c.f;
}

static __device__ __forceinline__ void addbias8(float* s, const float* b) {
  f32x4 x0 = *reinterpret_cast<const f32x4*>(b);
  f32x4 x1 = *reinterpret_cast<const f32x4*>(b + 4);
#pragma unroll
  for (int i = 0; i < 4; ++i) { s[i] += x0[i]; s[4 + i] += x1[i]; }
}

// Stage A of per-column absmax: fused over all three (2048 x 6144) matrices.
// grid = 3 mats x 8 row-chunks x 24 col-groups = 576 blocks, 256 threads.
// Each thread owns one column within a 256-row chunk (coalesced 1 KB/row per
// block, unroll-8 keeps 8 loads in flight), then one atomicMax per thread.
// fabsf() output is non-negative, so uint-bitpattern max == float max.
__global__ __launch_bounds__(256) void colmax_k(const float* __restrict__ s0,
                                                const float* __restrict__ s1,
                                                const float* __restrict__ s2,
                                                unsigned int* __restrict__ cmax) {
  int b = blockIdx.x;
  int cg = b % 24;           // column group (256 cols)
  int rc = (b / 24) & 7;     // row chunk (256 rows)
  int mat = b / 192;         // which matrix
  const float* src = (mat == 0) ? s0 : (mat == 1) ? s1 : s2;
  int col = cg * 256 + threadIdx.x;
  const float* p = src + (size_t)(rc * 256) * G3 + col;
  float m = 0.f;
#pragma unroll 8
  for (int k = 0; k < 256; ++k) m = fmaxf(m, fabsf(p[(size_t)k * G3]));
  atomicMax(cmax + mat * G3 + col, __float_as_uint(m));
}

// Stage B: colmax (uint bits, stored in the QI block) -> fscale = m/127^2 and
// qinv = 127/m (in place). 72 blocks x 256 threads cover 3*6144 columns.
__global__ void colscale_fin_k(float* __restrict__ fs,
                               unsigned int* __restrict__ qinv) {
  int i = blockIdx.x * 256 + threadIdx.x;
  float m = __uint_as_float(qinv[i]);
  fs[i] = m * (1.f / 16129.f);
  reinterpret_cast<float*>(qinv)[i] = 127.f / m;
}

// fp32 (2048 x 6144) -> int8 MFMA-tiled (per-column scaled).
// group idx = gg*(128*32*64) + (ct*32 + c)*64 + L ; lane L of chunk c holds
// B[k = c*64 + (L>>4)*16 + j][col = ct*16 + (L&15)], j=0..15 (16 B contiguous).
__global__ __launch_bounds__(256) void convert_w_i8(const float* __restrict__ src,
                                                    const float* __restrict__ qinv,
                                                    signed char* __restrict__ dst) {
  int tid = blockIdx.x * 256 + threadIdx.x;   // 786432 groups
  int gg = tid >> 18;
  int rem = tid & 262143;
  int ctc = rem >> 6;          // ct*32 + c
  int L = rem & 63;
  int ct = ctc >> 5, c = ctc & 31;
  int nl = L & 15, kq = L >> 4;
  int ocol = gg * 2048 + ct * 16 + nl;
  int kbase = c * 64 + kq * 16;
  float qi = qinv[ocol];
  union { signed char b[16]; int4 v; } o;
#pragma unroll
  for (int j = 0; j < 16; ++j) {
    int k = kbase + j;
    int q = (int)rintf(src[(size_t)k * G3 + ocol] * qi);
    o.b[j] = (signed char)q;
  }
  *reinterpret_cast<int4*>(dst + (size_t)tid * 16) = o.v;
}

// Convert fp32 weight (ksrc x 6144, row-major) -> bf16 MFMA-tiled layout (W0K only).
__global__ void convert_w(const float* __restrict__ src, unsigned short* __restrict__ dst,
                          int ksrc, int kc_shift) {
  int tid = blockIdx.x * 256 + threadIdx.x;
  int nl = tid & 15;
  int kb = (tid >> 4) & 3;
  int kc_mask = (1 << kc_shift) - 1;
  int c  = (tid >> 6) & kc_mask;
  int ct = tid >> (6 + kc_shift);
  int col = ct * 16 + nl;
  int kbase = c * 32 + kb * 8;
  union { unsigned short u[8]; int4 v; } o;
#pragma unroll
  for (int j = 0; j < 8; ++j) {
    int k = kbase + j;
    float v = (k < ksrc) ? src[(size_t)k * G3 + col] : 0.f;
    o.u[j] = f2bf(v);
  }
  *reinterpret_cast<int4*>(dst + (size_t)tid * 8) = o.v;
}

// X[t][b][e] = bf16(emb[tokens[b][t]][e]), e padded to 128 with zeros.
__global__ void embed_k(const int* __restrict__ tokens, const float* __restrict__ emb,
                        unsigned short* __restrict__ X) {
  int idx = blockIdx.x * 256 + threadIdx.x;
  int e = idx & (EP - 1);
  int b = (idx >> 7) & (BB - 1);
  int t = idx >> 14;
  float v = 0.f;
  if (e < EE) {
    int tok = tokens[b * TT + t];
    v = emb[(size_t)tok * EE + e];
  }
  X[idx] = f2bf(v);
}

// Store one f32x4 acc plane as bf16: C/D layout col=lane&15, row=kq*4+reg.
static __device__ __forceinline__ void store_plane(
    unsigned short* __restrict__ G, const f32x4& a, int ct16, int mt8, int lane) {
  int col = ct16 * 16 + (lane & 15);
  int kq = lane >> 4;
#pragma unroll
  for (int r = 0; r < 4; ++r) {
    int m = mt8 * 16 + kq * 4 + r;
    G[(size_t)m * UU + col] = f2bf(a[r]);
  }
}

// Pipelined step dispatch d (0..80): 768 blocks x 256 threads, 3 blocks/CU.
// blockIdx = g*256 + kh*64 + tu.  g: 0=L0, 1=L1-input, 2=L1-recurrent.
// int8 GEMM path: v_mfma_i32_16x16x64_i8, weights per-column int8, h int8
// (scale 1/127).  int32 accumulate is exact; epilogue dequantizes with
// fscale[col]=colmax/127^2 and stores bf16 partial planes (R9 scheme).
// W-stream halves to ~37 MB/dispatch vs bf16.
__global__ __launch_bounds__(256, 3) void step_gemms(
    int d,
    const unsigned short* __restrict__ X,
    const unsigned short* __restrict__ W0K,
    const signed char* __restrict__ QW0R, const signed char* __restrict__ QW1K,
    const signed char* __restrict__ QW1R,
    const float* __restrict__ FS0R, const float* __restrict__ FS1K,
    const float* __restrict__ FS1R,
    const signed char* __restrict__ H0Q, const signed char* __restrict__ H1Q,
    unsigned short* __restrict__ G0, unsigned short* __restrict__ G1I,
    unsigned short* __restrict__ G1R) {
  int tu = blockIdx.x & 63;
  int kh = (blockIdx.x >> 6) & 3;
  int g  = blockIdx.x >> 8;
  int lane = threadIdx.x & 63;
  int wave = threadIdx.x >> 6;   // mg: rows wave*32 .. +32
  int nl = lane & 15;
  int kq = lane >> 4;

  __shared__ unsigned char sbuf[2][24576];   // 2 x 24 KB weight windows

  const signed char* Aq;
  const signed char* QW;
  const float* FS;
  if (g == 0)      { if (d >= TT) return; Aq = H0Q; QW = QW0R; FS = FS0R; }
  else if (g == 1) { if (d <  1)  return; Aq = H0Q; QW = QW1K; FS = FS1K; }
  else             { if (d <  1)  return; Aq = H1Q; QW = QW1R; FS = FS1R; }

  i32x4 acc[2][2][3];   // [mt][nt][gate] int32 accumulators
#pragma unroll
  for (int mt = 0; mt < 2; ++mt)
#pragma unroll
    for (int nt = 0; nt < 2; ++nt)
#pragma unroll
      for (int gg = 0; gg < 3; ++gg) acc[mt][nt][gg] = {0, 0, 0, 0};

  const signed char* ap[2];
#pragma unroll
  for (int mt = 0; mt < 2; ++mt)
    ap[mt] = Aq + (size_t)(wave * 32 + mt * 16 + nl) * UU + kq * 16;

  // staging map: 6 int4 per thread cover one 24 KB window (4 chunks of K=64)
  // slot = (kcw*2 + nt)*3 + gg ; window advance = 4 chunks = 4096 B
  int woff[6];
  int soff0 = threadIdx.x * 16;   // bytes; ss*16 = slot*1024 + l16*16
  {
    int t = threadIdx.x;
#pragma unroll
    for (int i = 0; i < 6; ++i) {
      int ss = i * 256 + t;
      int slot = ss >> 6, l16 = ss & 63;
      int gg = slot % 3, q = slot / 3;
      int nt = q & 1, kcw = q >> 1;
      woff[i] = gg * 4194304 + (((tu * 2 + nt) * 32 + kh * 8 + kcw) * 64 + l16) * 16;
    }
  }

  i32x4 areg[4][2];
  // prologue: A chunks (kh*8 + 0..3) first, then W window 0
#pragma unroll
  for (int kcw = 0; kcw < 4; ++kcw)
#pragma unroll
    for (int mt = 0; mt < 2; ++mt)
      areg[kcw][mt] = *reinterpret_cast<const i32x4*>(ap[mt] + (size_t)(kh * 8 + kcw) * 64);
  {
    int4 v[6];
#pragma unroll
    for (int i = 0; i < 6; ++i) v[i] = *reinterpret_cast<const int4*>(QW + (size_t)woff[i]);
#pragma unroll
    for (int i = 0; i < 6; ++i)
      *reinterpret_cast<int4*>(&sbuf[0][soff0 + i * 4096]) = v[i];
  }
  __syncthreads();

#pragma unroll
  for (int w = 0; w < 2; ++w) {
    i32x4 anext[4][2];
    int4 v[6];
    if (w == 0) {
#pragma unroll
      for (int kcw = 0; kcw < 4; ++kcw)
#pragma unroll
        for (int mt = 0; mt < 2; ++mt)
          anext[kcw][mt] = *reinterpret_cast<const i32x4*>(
              ap[mt] + (size_t)(kh * 8 + 4 + kcw) * 64);
#pragma unroll
      for (int i = 0; i < 6; ++i)
        v[i] = *reinterpret_cast<const int4*>(QW + (size_t)woff[i] + 4096);
    }
#pragma unroll
    for (int kcw = 0; kcw < 4; ++kcw) {
#pragma unroll
      for (int nt = 0; nt < 2; ++nt) {
#pragma unroll
        for (int gg = 0; gg < 3; ++gg) {
          i32x4 b = *reinterpret_cast<const i32x4*>(
              &sbuf[w & 1][((kcw * 2 + nt) * 3 + gg) * 1024 + lane * 16]);
#pragma unroll
          for (int mt = 0; mt < 2; ++mt)
            acc[mt][nt][gg] = __builtin_amdgcn_mfma_i32_16x16x64_i8(
                areg[kcw][mt], b, acc[mt][nt][gg], 0, 0, 0);
        }
      }
    }
    if (w == 0) {
#pragma unroll
      for (int i = 0; i < 6; ++i)
        *reinterpret_cast<int4*>(&sbuf[1][soff0 + i * 4096]) = v[i];
#pragma unroll
      for (int kcw = 0; kcw < 4; ++kcw)
#pragma unroll
        for (int mt = 0; mt < 2; ++mt) areg[kcw][mt] = anext[kcw][mt];
      __syncthreads();
    }
  }

  // L0 input projection (bf16, K=128 padded), kh==0 blocks, after main loop
  // so its registers don't inflate the K-loop's live set.
  f32x4 acci[2][2][2];   // [mt][nt][z/r]
  bool do_inp = (g == 0 && kh == 0);
  if (do_inp) {
#pragma unroll
    for (int nt = 0; nt < 2; ++nt) {
      const unsigned short* wp = W0K + (size_t)(tu * 2 + nt) * 4 * 512 + (size_t)lane * 8;
#pragma unroll
      for (int mt = 0; mt < 2; ++mt) {
        const unsigned short* xp = X + (size_t)d * BB * EP
                                 + (size_t)(wave * 32 + mt * 16 + nl) * EP + kq * 8;
        f32x4 t0 = {0,0,0,0}, t1 = {0,0,0,0}, t2 = {0,0,0,0};
#pragma unroll
        for (int c = 0; c < 4; ++c) {
          bf16x8 a  = *reinterpret_cast<const bf16x8*>(xp + c * 32);
          bf16x8 b0 = *reinterpret_cast<const bf16x8*>(wp + (size_t)0 * (128 * 4 * 512) + c * 512);
          bf16x8 b1 = *reinterpret_cast<const bf16x8*>(wp + (size_t)1 * (128 * 4 * 512) + c * 512);
          bf16x8 b2 = *reinterpret_cast<const bf16x8*>(wp + (size_t)2 * (128 * 4 * 512) + c * 512);
          t0 = __builtin_amdgcn_mfma_f32_16x16x32_bf16(a, b0, t0, 0, 0, 0);
          t1 = __builtin_amdgcn_mfma_f32_16x16x32_bf16(a, b1, t1, 0, 0, 0);
          t2 = __builtin_amdgcn_mfma_f32_16x16x32_bf16(a, b2, t2, 0, 0, 0);
        }
        acci[mt][nt][0] = t0;
        acci[mt][nt][1] = t1;
        store_plane(G0 + (size_t)12 * PLANE, t2, tu * 2 + nt, wave * 2 + mt, lane);
      }
    }
  }

  // epilogue: dequantize + bf16 partial planes (plane = gate*4 + kh)
#pragma unroll
  for (int mt = 0; mt < 2; ++mt) {
#pragma unroll
    for (int nt = 0; nt < 2; ++nt) {
      int ct16 = tu * 2 + nt;
      int col = ct16 * 16 + nl;
      int mt8 = wave * 2 + mt;
      float fs0 = FS[0 * UU + col], fs1 = FS[1 * UU + col], fs2 = FS[2 * UU + col];
      f32x4 p0, p1, p2;
#pragma unroll
      for (int i = 0; i < 4; ++i) {
        p0[i] = (float)acc[mt][nt][0][i] * fs0;
        p1[i] = (float)acc[mt][nt][1][i] * fs1;
        p2[i] = (float)acc[mt][nt][2][i] * fs2;
      }
      if (do_inp) { p0 += acci[mt][nt][0]; p1 += acci[mt][nt][1]; }
      unsigned short* base = (g == 0) ? G0 : (g == 1) ? G1I : G1R;
      store_plane(base + (size_t)(0 + kh) * PLANE, p0, ct16, mt8, lane);
      store_plane(base + (size_t)(4 + kh) * PLANE, p1, ct16, mt8, lane);
      store_plane(base + (size_t)(8 + kh) * PLANE, p2, ct16, mt8, lane);
    }
  }
}

// Gate math + state update for dispatch d: h0(d) [d<80] and h1(d-1) [d>=1].
// Writes fp32 state + int8 quantized state (scale 127).
__global__ __launch_bounds__(128) void gates_k(
    int d,
    const unsigned short* __restrict__ G0, const unsigned short* __restrict__ G1I,
    const unsigned short* __restrict__ G1R,
    const float* __restrict__ b0, const float* __restrict__ b1,
    float* __restrict__ H0F, signed char* __restrict__ H0Q,
    float* __restrict__ H1F, signed char* __restrict__ H1Q) {
  int t = blockIdx.x * 128 + threadIdx.x;   // 32768 threads
  size_t idx = (size_t)t * 8;
  int u = (int)(idx & (UU - 1));

  if (d < TT) {
    float zs[8] = {0,0,0,0,0,0,0,0}, rs[8] = {0,0,0,0,0,0,0,0};
    float hh[8] = {0,0,0,0,0,0,0,0}, ih[8] = {0,0,0,0,0,0,0,0};
#pragma unroll
    for (int p = 0; p < 4; ++p) {
      acc8(zs, G0 + (size_t)p * PLANE + idx);
      acc8(rs, G0 + (size_t)(4 + p) * PLANE + idx);
      acc8(hh, G0 + (size_t)(8 + p) * PLANE + idx);
    }
    acc8(ih, G0 + (size_t)12 * PLANE + idx);
    addbias8(zs, b0 + u);          addbias8(zs, b0 + G3 + u);
    addbias8(rs, b0 + UU + u);     addbias8(rs, b0 + G3 + UU + u);
    addbias8(ih, b0 + 2 * UU + u);
    addbias8(hh, b0 + G3 + 2 * UU + u);
    f32x4 h0 = *reinterpret_cast<const f32x4*>(H0F + idx);
    f32x4 h1 = *reinterpret_cast<const f32x4*>(H0F + idx + 4);
    float hold[8] = {h0[0], h0[1], h0[2], h0[3], h1[0], h1[1], h1[2], h1[3]};
    float hn[8];
#pragma unroll
    for (int i = 0; i < 8; ++i) {
      float z = sigf(zs[i]), r = sigf(rs[i]);
      float cand = tanhfast(ih[i] + r * hh[i]);
      hn[i] = z * hold[i] + (1.f - z) * cand;
    }
    unsigned int qa = 0, qb = 0;
#pragma unroll
    for (int i = 0; i < 4; ++i) {
      qa |= ((unsigned int)((int)rintf(hn[i] * 127.f) & 0xff)) << (8 * i);
      qb |= ((unsigned int)((int)rintf(hn[4 + i] * 127.f) & 0xff)) << (8 * i);
    }
    *reinterpret_cast<f32x4*>(H0F + idx)     = f32x4{hn[0], hn[1], hn[2], hn[3]};
    *reinterpret_cast<f32x4*>(H0F + idx + 4) = f32x4{hn[4], hn[5], hn[6], hn[7]};
    *reinterpret_cast<uint2*>(H0Q + idx) = make_uint2(qa, qb);
  }
  if (d >= 1) {
    float iz[8] = {0,0,0,0,0,0,0,0}, ir[8] = {0,0,0,0,0,0,0,0}, ih[8] = {0,0,0,0,0,0,0,0};
    float hz[8] = {0,0,0,0,0,0,0,0}, hr[8] = {0,0,0,0,0,0,0,0}, hh[8] = {0,0,0,0,0,0,0,0};
#pragma unroll
    for (int p = 0; p < 4; ++p) {
      acc8(iz, G1I + (size_t)p * PLANE + idx);
      acc8(ir, G1I + (size_t)(4 + p) * PLANE + idx);
      acc8(ih, G1I + (size_t)(8 + p) * PLANE + idx);
      acc8(hz, G1R + (size_t)p * PLANE + idx);
      acc8(hr, G1R + (size_t)(4 + p) * PLANE + idx);
      acc8(hh, G1R + (size_t)(8 + p) * PLANE + idx);
    }
    addbias8(iz, b1 + u);           addbias8(hz, b1 + G3 + u);
    addbias8(ir, b1 + UU + u);      addbias8(hr, b1 + G3 + UU + u);
    addbias8(ih, b1 + 2 * UU + u);  addbias8(hh, b1 + G3 + 2 * UU + u);
    f32x4 h0 = *reinterpret_cast<const f32x4*>(H1F + idx);
    f32x4 h1 = *reinterpret_cast<const f32x4*>(H1F + idx + 4);
    float hold[8] = {h0[0], h0[1], h0[2], h0[3], h1[0], h1[1], h1[2], h1[3]};
    float hn[8];
#pragma unroll
    for (int i = 0; i < 8; ++i) {
      float z = sigf(iz[i] + hz[i]), r = sigf(ir[i] + hr[i]);
      float cand = tanhfast(ih[i] + r * hh[i]);
      hn[i] = z * hold[i] + (1.f - z) * cand;
    }
    unsigned int qa = 0, qb = 0;
#pragma unroll
    for (int i = 0; i < 4; ++i) {
      qa |= ((unsigned int)((int)rintf(hn[i] * 127.f) & 0xff)) << (8 * i);
      qb |= ((unsigned int)((int)rintf(hn[4 + i] * 127.f) & 0xff)) << (8 * i);
    }
    *reinterpret_cast<f32x4*>(H1F + idx)     = f32x4{hn[0], hn[1], hn[2], hn[3]};
    *reinterpret_cast<f32x4*>(H1F + idx + 4) = f32x4{hn[4], hn[5], hn[6], hn[7]};
    *reinterpret_cast<uint2*>(H1Q + idx) = make_uint2(qa, qb);
  }
}

// logits = sigmoid(h1 @ wout + bout): 128 blocks x 64 threads, one row each.
__global__ void out_k(const float* __restrict__ h1, const float* __restrict__ wout,
                      const float* __restrict__ bout, float* __restrict__ out) {
  int row = blockIdx.x;
  int lane = threadIdx.x;
  float s = 0.f;
  for (int i = lane; i < UU; i += 64) s += h1[(size_t)row * UU + i] * wout[i];
#pragma unroll
  for (int off = 32; off > 0; off >>= 1) s += __shfl_down(s, off);
  if (lane == 0) out[row] = 1.f / (1.f + __expf(-(s + bout[0])));
}

extern "C" void kernel_launch(void* const* d_in, const int* in_sizes, int n_in,
                              void* d_out, int out_size, void* d_ws, size_t ws_size,
                              hipStream_t stream) {
  const int*   tokens = (const int*)  d_in[0];
  const float* emb    = (const float*)d_in[1];
  const float* k0     = (const float*)d_in[2];
  const float* r0     = (const float*)d_in[3];
  const float* b0     = (const float*)d_in[4];
  const float* k1     = (const float*)d_in[5];
  const float* r1     = (const float*)d_in[6];
  const float* b1     = (const float*)d_in[7];
  const float* wout   = (const float*)d_in[8];
  const float* bout   = (const float*)d_in[9];
  float* out = (float*)d_out;

  char* ws = (char*)d_ws;
  unsigned short* W0K = (unsigned short*)(ws + 0);           //  1.5 MB bf16 tiled
  signed char* QW0R   = (signed char*)(ws + 1572864);        // 12.6 MB int8 tiled
  signed char* QW1K   = (signed char*)(ws + 14155776);       // 12.6 MB
  signed char* QW1R   = (signed char*)(ws + 26738688);       // 12.6 MB
  float* FS0R         = (float*)(ws + 39321600);             // 24 KB dequant scales
  float* FS1K         = (float*)(ws + 39346176);
  float* FS1R         = (float*)(ws + 39370752);
  float* QI0R         = (float*)(ws + 39395328);             // 24 KB quant inv-scales
  float* QI1K         = (float*)(ws + 39419904);
  float* QI1R         = (float*)(ws + 39444480);
  unsigned short* X   = (unsigned short*)(ws + 39469056);    //  2.6 MB bf16
  float* H0F          = (float*)(ws + 42090496);             //  1 MB fp32 state
  float* H1F          = (float*)(ws + 43139072);             //  1 MB
  signed char* H0Q    = (signed char*)(ws + 44187648);       //  0.25 MB int8 state
  signed char* H1Q    = (signed char*)(ws + 44449792);       //  0.25 MB
  unsigned short* G0  = (unsigned short*)(ws + 44711936);    // 13 bf16 planes (6.5 MB)
  unsigned short* G1I = (unsigned short*)(ws + 51527680);    // 12 bf16 planes (6 MB)
  unsigned short* G1R = (unsigned short*)(ws + 57819136);    // 12 bf16 planes (6 MB)
  // total ws use: 64,110,592 bytes

  // zero h state (H0F, H1F, H0Q, H1Q contiguous): 2.5 MiB
  hipMemsetAsync(ws + 42090496, 0, 2621440, stream);
  // zero colmax accumulators (QI0R/QI1K/QI1R contiguous, 3 x 24 KB)
  hipMemsetAsync(ws + 39395328, 0, 73728, stream);

  // per-column absmax: fused high-parallelism two-stage reduction
  // (576 blocks, coalesced, atomicMax on uint bits), then finalize scales.
  colmax_k<<<576, 256, 0, stream>>>(r0, k1, r1, (unsigned int*)QI0R);
  colscale_fin_k<<<72, 256, 0, stream>>>(FS0R, (unsigned int*)QI0R);

  // int8 tiled conversion (big matrices)
  convert_w_i8<<<3072, 256, 0, stream>>>(r0, QI0R, QW0R);
  convert_w_i8<<<3072, 256, 0, stream>>>(k1, QI1K, QW1K);
  convert_w_i8<<<3072, 256, 0, stream>>>(r1, QI1R, QW1R);

  // L0 input-proj weights stay bf16 (tiny, K=128 padded)
  convert_w<<<384, 256, 0, stream>>>(k0, W0K, 100, 2);

  // embedding gather (time-major, padded)
  embed_k<<<5120, 256, 0, stream>>>(tokens, emb, X);

  // 81 pipelined step dispatches: d computes h0(d) and h1(d-1) concurrently
  for (int d = 0; d <= TT; ++d) {
    step_gemms<<<768, 256, 0, stream>>>(d, X, W0K, QW0R, QW1K, QW1R,
                                        FS0R, FS1K, FS1R, H0Q, H1Q,
                                        G0, G1I, G1R);
    gates_k<<<256, 128, 0, stream>>>(d, G0, G1I, G1R, b0, b1,
                                     H0F, H0Q, H1F, H1Q);
  }

  out_k<<<128, 64, 0, stream>>>(H1F, wout, bout, out);
}

// Round 2
// 2187.649 us; speedup vs baseline: 1.1589x; 1.0225x over previous
//
#include <hip/hip_runtime.h>
#include <cstdint>
#include <cstddef>

#define BB 128    // batch
#define TT 80     // seq
#define EE 100    // emb dim
#define EP 128    // padded emb dim
#define UU 2048   // units
#define G3 6144   // 3*UU
#define PLANE (BB * UU)   // 262144 elements, one gate pre-activation plane

typedef __bf16 bf16x8 __attribute__((ext_vector_type(8)));
typedef float f32x4 __attribute__((ext_vector_type(4)));
typedef int   i32x4 __attribute__((ext_vector_type(4)));

static __device__ __forceinline__ unsigned short f2bf(float x) {
  union { float f; unsigned int u; } a; a.f = x;
  unsigned int r = a.u + 0x7fffu + ((a.u >> 16) & 1u);  // RNE
  return (unsigned short)(r >> 16);
}

static __device__ __forceinline__ float sigf(float x) {
  return 1.f / (1.f + __expf(-x));
}
static __device__ __forceinline__ float tanhfast(float x) {
  return 1.f - 2.f / (__expf(2.f * x) + 1.f);
}

// accumulate 8 bf16 plane values (one int4 load) into float[8]
static __device__ __forceinline__ void acc8(float* s, const unsigned short* p) {
  int4 v = *reinterpret_cast<const int4*>(p);
  unsigned int w0 = (unsigned int)v.x, w1 = (unsigned int)v.y,
               w2 = (unsigned int)v.z, w3 = (unsigned int)v.w;
  union { unsigned int u; float f; } c;
  c.u = w0 << 16;         s[0] += c.f;
  c.u = w0 & 0xffff0000u; s[1] += c.f;
  c.u = w1 << 16;         s[2] += c.f;
  c.u = w1 & 0xffff0000u; s[3] += c.f;
  c.u = w2 << 16;         s[4] += c.f;
  c.u = w2 & 0xffff0000u; s[5] += c.f;
  c.u = w3 << 16;         s[6] += c.f;
  c.u = w3 & 0xffff0000u; s[7] += c.f;
}

static __device__ __forceinline__ void addbias8(float* s, const float* b) {
  f32x4 x0 = *reinterpret_cast<const f32x4*>(b);
  f32x4 x1 = *reinterpret_cast<const f32x4*>(b + 4);
#pragma unroll
  for (int i = 0; i < 4; ++i) { s[i] += x0[i]; s[4 + i] += x1[i]; }
}

// Stage A of per-column absmax, v2: fused over all three (2048 x 6144)
// matrices, float4 loads, full occupancy.
// grid = 3 mats x 32 row-chunks (64 rows) x 24 col-groups (256 cols) = 2304
// blocks x 256 threads (9216 waves ~ full machine). Thread t owns float4
// column fc = t&63 within its group and rows r0 = t>>6 (stride 4): 16 x f32x4
// coalesced loads (1 KB per wave-instruction). LDS reduce 4-way, then one
// atomicMax per column per block (~32 per column total).
// fabsf() output is non-negative, so uint-bitpattern max == float max.
__global__ __launch_bounds__(256) void colmax_k(const float* __restrict__ s0,
                                                const float* __restrict__ s1,
                                                const float* __restrict__ s2,
                                                unsigned int* __restrict__ cmax) {
  int b = blockIdx.x;
  int cg = b % 24;           // column group (256 cols)
  int rc = (b / 24) & 31;    // row chunk (64 rows)
  int mat = b / 768;         // which matrix
  const float* src = (mat == 0) ? s0 : (mat == 1) ? s1 : s2;
  int fc = threadIdx.x & 63;   // float4 column within group
  int r0 = threadIdx.x >> 6;   // 0..3
  const char* base = (const char*)src
      + ((size_t)(rc * 64 + r0) * G3 + cg * 256 + fc * 4) * 4;
  f32x4 m = {0.f, 0.f, 0.f, 0.f};
#pragma unroll
  for (int k = 0; k < 16; ++k) {
    f32x4 v = *reinterpret_cast<const f32x4*>(base + (size_t)k * (4 * G3 * 4));
#pragma unroll
    for (int i = 0; i < 4; ++i) m[i] = fmaxf(m[i], fabsf(v[i]));
  }
  __shared__ f32x4 red[256];
  red[threadIdx.x] = m;
  __syncthreads();
  if (threadIdx.x < 64) {
    int t = threadIdx.x;
    f32x4 a = red[t], b2 = red[t + 64], c2 = red[t + 128], d2 = red[t + 192];
    unsigned int* out = cmax + mat * G3 + cg * 256 + t * 4;
#pragma unroll
    for (int i = 0; i < 4; ++i) {
      float mm = fmaxf(fmaxf(a[i], b2[i]), fmaxf(c2[i], d2[i]));
      atomicMax(out + i, __float_as_uint(mm));
    }
  }
}

// Stage B: colmax (uint bits, stored in the QI block) -> fscale = m/127^2 and
// qinv = 127/m (in place). 72 blocks x 256 threads cover 3*6144 columns.
__global__ void colscale_fin_k(float* __restrict__ fs,
                               unsigned int* __restrict__ qinv) {
  int i = blockIdx.x * 256 + threadIdx.x;
  float m = __uint_as_float(qinv[i]);
  fs[i] = m * (1.f / 16129.f);
  reinterpret_cast<float*>(qinv)[i] = 127.f / m;
}

// fp32 (2048 x 6144) -> int8 MFMA-tiled (per-column scaled), all 3 matrices
// in one launch (9216 blocks). blockIdx/3072 picks the matrix.
// group idx = gg*(128*32*64) + (ct*32 + c)*64 + L ; lane L of chunk c holds
// B[k = c*64 + (L>>4)*16 + j][col = ct*16 + (L&15)], j=0..15 (16 B contiguous).
__global__ __launch_bounds__(256) void convert_w_i8(const float* __restrict__ s0,
                                                    const float* __restrict__ s1,
                                                    const float* __restrict__ s2,
                                                    const float* __restrict__ qinv,
                                                    signed char* __restrict__ dst) {
  int mb = blockIdx.x / 3072;
  int tid = (blockIdx.x - mb * 3072) * 256 + threadIdx.x;   // 786432 groups/mat
  const float* src = (mb == 0) ? s0 : (mb == 1) ? s1 : s2;
  const float* qi_ = qinv + mb * G3;
  signed char* d_ = dst + (size_t)mb * 12582912;
  int gg = tid >> 18;
  int rem = tid & 262143;
  int ctc = rem >> 6;          // ct*32 + c
  int L = rem & 63;
  int ct = ctc >> 5, c = ctc & 31;
  int nl = L & 15, kq = L >> 4;
  int ocol = gg * 2048 + ct * 16 + nl;
  int kbase = c * 64 + kq * 16;
  float qi = qi_[ocol];
  union { signed char b[16]; int4 v; } o;
#pragma unroll
  for (int j = 0; j < 16; ++j) {
    int k = kbase + j;
    int q = (int)rintf(src[(size_t)k * G3 + ocol] * qi);
    o.b[j] = (signed char)q;
  }
  *reinterpret_cast<int4*>(d_ + (size_t)tid * 16) = o.v;
}

// Convert fp32 weight (ksrc x 6144, row-major) -> bf16 MFMA-tiled layout (W0K only).
__global__ void convert_w(const float* __restrict__ src, unsigned short* __restrict__ dst,
                          int ksrc, int kc_shift) {
  int tid = blockIdx.x * 256 + threadIdx.x;
  int nl = tid & 15;
  int kb = (tid >> 4) & 3;
  int kc_mask = (1 << kc_shift) - 1;
  int c  = (tid >> 6) & kc_mask;
  int ct = tid >> (6 + kc_shift);
  int col = ct * 16 + nl;
  int kbase = c * 32 + kb * 8;
  union { unsigned short u[8]; int4 v; } o;
#pragma unroll
  for (int j = 0; j < 8; ++j) {
    int k = kbase + j;
    float v = (k < ksrc) ? src[(size_t)k * G3 + col] : 0.f;
    o.u[j] = f2bf(v);
  }
  *reinterpret_cast<int4*>(dst + (size_t)tid * 8) = o.v;
}

// X[t][b][e] = bf16(emb[tokens[b][t]][e]), e padded to 128 with zeros.
__global__ void embed_k(const int* __restrict__ tokens, const float* __restrict__ emb,
                        unsigned short* __restrict__ X) {
  int idx = blockIdx.x * 256 + threadIdx.x;
  int e = idx & (EP - 1);
  int b = (idx >> 7) & (BB - 1);
  int t = idx >> 14;
  float v = 0.f;
  if (e < EE) {
    int tok = tokens[b * TT + t];
    v = emb[(size_t)tok * EE + e];
  }
  X[idx] = f2bf(v);
}

// Store one f32x4 acc plane as bf16: C/D layout col=lane&15, row=kq*4+reg.
static __device__ __forceinline__ void store_plane(
    unsigned short* __restrict__ G, const f32x4& a, int ct16, int mt8, int lane) {
  int col = ct16 * 16 + (lane & 15);
  int kq = lane >> 4;
#pragma unroll
  for (int r = 0; r < 4; ++r) {
    int m = mt8 * 16 + kq * 4 + r;
    G[(size_t)m * UU + col] = f2bf(a[r]);
  }
}

// Pipelined step dispatch d (0..80): 768 blocks x 256 threads, 3 blocks/CU.
// blockIdx = g*256 + kh*64 + tu.  g: 0=L0, 1=L1-input, 2=L1-recurrent.
// int8 GEMM path: v_mfma_i32_16x16x64_i8, weights per-column int8, h int8
// (scale 1/127).  int32 accumulate is exact; epilogue dequantizes with
// fscale[col]=colmax/127^2 and stores bf16 partial planes (R9 scheme).
// W-stream halves to ~37 MB/dispatch vs bf16.
__global__ __launch_bounds__(256, 3) void step_gemms(
    int d,
    const unsigned short* __restrict__ X,
    const unsigned short* __restrict__ W0K,
    const signed char* __restrict__ QW0R, const signed char* __restrict__ QW1K,
    const signed char* __restrict__ QW1R,
    const float* __restrict__ FS0R, const float* __restrict__ FS1K,
    const float* __restrict__ FS1R,
    const signed char* __restrict__ H0Q, const signed char* __restrict__ H1Q,
    unsigned short* __restrict__ G0, unsigned short* __restrict__ G1I,
    unsigned short* __restrict__ G1R) {
  int tu = blockIdx.x & 63;
  int kh = (blockIdx.x >> 6) & 3;
  int g  = blockIdx.x >> 8;
  int lane = threadIdx.x & 63;
  int wave = threadIdx.x >> 6;   // mg: rows wave*32 .. +32
  int nl = lane & 15;
  int kq = lane >> 4;

  __shared__ unsigned char sbuf[2][24576];   // 2 x 24 KB weight windows

  const signed char* Aq;
  const signed char* QW;
  const float* FS;
  if (g == 0)      { if (d >= TT) return; Aq = H0Q; QW = QW0R; FS = FS0R; }
  else if (g == 1) { if (d <  1)  return; Aq = H0Q; QW = QW1K; FS = FS1K; }
  else             { if (d <  1)  return; Aq = H1Q; QW = QW1R; FS = FS1R; }

  i32x4 acc[2][2][3];   // [mt][nt][gate] int32 accumulators
#pragma unroll
  for (int mt = 0; mt < 2; ++mt)
#pragma unroll
    for (int nt = 0; nt < 2; ++nt)
#pragma unroll
      for (int gg = 0; gg < 3; ++gg) acc[mt][nt][gg] = {0, 0, 0, 0};

  const signed char* ap[2];
#pragma unroll
  for (int mt = 0; mt < 2; ++mt)
    ap[mt] = Aq + (size_t)(wave * 32 + mt * 16 + nl) * UU + kq * 16;

  // staging map: 6 int4 per thread cover one 24 KB window (4 chunks of K=64)
  // slot = (kcw*2 + nt)*3 + gg ; window advance = 4 chunks = 4096 B
  int woff[6];
  int soff0 = threadIdx.x * 16;   // bytes; ss*16 = slot*1024 + l16*16
  {
    int t = threadIdx.x;
#pragma unroll
    for (int i = 0; i < 6; ++i) {
      int ss = i * 256 + t;
      int slot = ss >> 6, l16 = ss & 63;
      int gg = slot % 3, q = slot / 3;
      int nt = q & 1, kcw = q >> 1;
      woff[i] = gg * 4194304 + (((tu * 2 + nt) * 32 + kh * 8 + kcw) * 64 + l16) * 16;
    }
  }

  i32x4 areg[4][2];
  // prologue: A chunks (kh*8 + 0..3) first, then W window 0
#pragma unroll
  for (int kcw = 0; kcw < 4; ++kcw)
#pragma unroll
    for (int mt = 0; mt < 2; ++mt)
      areg[kcw][mt] = *reinterpret_cast<const i32x4*>(ap[mt] + (size_t)(kh * 8 + kcw) * 64);
  {
    int4 v[6];
#pragma unroll
    for (int i = 0; i < 6; ++i) v[i] = *reinterpret_cast<const int4*>(QW + (size_t)woff[i]);
#pragma unroll
    for (int i = 0; i < 6; ++i)
      *reinterpret_cast<int4*>(&sbuf[0][soff0 + i * 4096]) = v[i];
  }
  __syncthreads();

#pragma unroll
  for (int w = 0; w < 2; ++w) {
    i32x4 anext[4][2];
    int4 v[6];
    if (w == 0) {
#pragma unroll
      for (int kcw = 0; kcw < 4; ++kcw)
#pragma unroll
        for (int mt = 0; mt < 2; ++mt)
          anext[kcw][mt] = *reinterpret_cast<const i32x4*>(
              ap[mt] + (size_t)(kh * 8 + 4 + kcw) * 64);
#pragma unroll
      for (int i = 0; i < 6; ++i)
        v[i] = *reinterpret_cast<const int4*>(QW + (size_t)woff[i] + 4096);
    }
#pragma unroll
    for (int kcw = 0; kcw < 4; ++kcw) {
#pragma unroll
      for (int nt = 0; nt < 2; ++nt) {
#pragma unroll
        for (int gg = 0; gg < 3; ++gg) {
          i32x4 b = *reinterpret_cast<const i32x4*>(
              &sbuf[w & 1][((kcw * 2 + nt) * 3 + gg) * 1024 + lane * 16]);
#pragma unroll
          for (int mt = 0; mt < 2; ++mt)
            acc[mt][nt][gg] = __builtin_amdgcn_mfma_i32_16x16x64_i8(
                areg[kcw][mt], b, acc[mt][nt][gg], 0, 0, 0);
        }
      }
    }
    if (w == 0) {
#pragma unroll
      for (int i = 0; i < 6; ++i)
        *reinterpret_cast<int4*>(&sbuf[1][soff0 + i * 4096]) = v[i];
#pragma unroll
      for (int kcw = 0; kcw < 4; ++kcw)
#pragma unroll
        for (int mt = 0; mt < 2; ++mt) areg[kcw][mt] = anext[kcw][mt];
      __syncthreads();
    }
  }

  // L0 input projection (bf16, K=128 padded), kh==0 blocks, after main loop
  // so its registers don't inflate the K-loop's live set.
  f32x4 acci[2][2][2];   // [mt][nt][z/r]
  bool do_inp = (g == 0 && kh == 0);
  if (do_inp) {
#pragma unroll
    for (int nt = 0; nt < 2; ++nt) {
      const unsigned short* wp = W0K + (size_t)(tu * 2 + nt) * 4 * 512 + (size_t)lane * 8;
#pragma unroll
      for (int mt = 0; mt < 2; ++mt) {
        const unsigned short* xp = X + (size_t)d * BB * EP
                                 + (size_t)(wave * 32 + mt * 16 + nl) * EP + kq * 8;
        f32x4 t0 = {0,0,0,0}, t1 = {0,0,0,0}, t2 = {0,0,0,0};
#pragma unroll
        for (int c = 0; c < 4; ++c) {
          bf16x8 a  = *reinterpret_cast<const bf16x8*>(xp + c * 32);
          bf16x8 b0 = *reinterpret_cast<const bf16x8*>(wp + (size_t)0 * (128 * 4 * 512) + c * 512);
          bf16x8 b1 = *reinterpret_cast<const bf16x8*>(wp + (size_t)1 * (128 * 4 * 512) + c * 512);
          bf16x8 b2 = *reinterpret_cast<const bf16x8*>(wp + (size_t)2 * (128 * 4 * 512) + c * 512);
          t0 = __builtin_amdgcn_mfma_f32_16x16x32_bf16(a, b0, t0, 0, 0, 0);
          t1 = __builtin_amdgcn_mfma_f32_16x16x32_bf16(a, b1, t1, 0, 0, 0);
          t2 = __builtin_amdgcn_mfma_f32_16x16x32_bf16(a, b2, t2, 0, 0, 0);
        }
        acci[mt][nt][0] = t0;
        acci[mt][nt][1] = t1;
        store_plane(G0 + (size_t)12 * PLANE, t2, tu * 2 + nt, wave * 2 + mt, lane);
      }
    }
  }

  // epilogue: dequantize + bf16 partial planes (plane = gate*4 + kh)
#pragma unroll
  for (int mt = 0; mt < 2; ++mt) {
#pragma unroll
    for (int nt = 0; nt < 2; ++nt) {
      int ct16 = tu * 2 + nt;
      int col = ct16 * 16 + nl;
      int mt8 = wave * 2 + mt;
      float fs0 = FS[0 * UU + col], fs1 = FS[1 * UU + col], fs2 = FS[2 * UU + col];
      f32x4 p0, p1, p2;
#pragma unroll
      for (int i = 0; i < 4; ++i) {
        p0[i] = (float)acc[mt][nt][0][i] * fs0;
        p1[i] = (float)acc[mt][nt][1][i] * fs1;
        p2[i] = (float)acc[mt][nt][2][i] * fs2;
      }
      if (do_inp) { p0 += acci[mt][nt][0]; p1 += acci[mt][nt][1]; }
      unsigned short* base = (g == 0) ? G0 : (g == 1) ? G1I : G1R;
      store_plane(base + (size_t)(0 + kh) * PLANE, p0, ct16, mt8, lane);
      store_plane(base + (size_t)(4 + kh) * PLANE, p1, ct16, mt8, lane);
      store_plane(base + (size_t)(8 + kh) * PLANE, p2, ct16, mt8, lane);
    }
  }
}

// Gate math + state update for dispatch d: h0(d) [d<80] and h1(d-1) [d>=1].
// Writes fp32 state + int8 quantized state (scale 127).
__global__ __launch_bounds__(128) void gates_k(
    int d,
    const unsigned short* __restrict__ G0, const unsigned short* __restrict__ G1I,
    const unsigned short* __restrict__ G1R,
    const float* __restrict__ b0, const float* __restrict__ b1,
    float* __restrict__ H0F, signed char* __restrict__ H0Q,
    float* __restrict__ H1F, signed char* __restrict__ H1Q) {
  int t = blockIdx.x * 128 + threadIdx.x;   // 32768 threads
  size_t idx = (size_t)t * 8;
  int u = (int)(idx & (UU - 1));

  if (d < TT) {
    float zs[8] = {0,0,0,0,0,0,0,0}, rs[8] = {0,0,0,0,0,0,0,0};
    float hh[8] = {0,0,0,0,0,0,0,0}, ih[8] = {0,0,0,0,0,0,0,0};
#pragma unroll
    for (int p = 0; p < 4; ++p) {
      acc8(zs, G0 + (size_t)p * PLANE + idx);
      acc8(rs, G0 + (size_t)(4 + p) * PLANE + idx);
      acc8(hh, G0 + (size_t)(8 + p) * PLANE + idx);
    }
    acc8(ih, G0 + (size_t)12 * PLANE + idx);
    addbias8(zs, b0 + u);          addbias8(zs, b0 + G3 + u);
    addbias8(rs, b0 + UU + u);     addbias8(rs, b0 + G3 + UU + u);
    addbias8(ih, b0 + 2 * UU + u);
    addbias8(hh, b0 + G3 + 2 * UU + u);
    f32x4 h0 = *reinterpret_cast<const f32x4*>(H0F + idx);
    f32x4 h1 = *reinterpret_cast<const f32x4*>(H0F + idx + 4);
    float hold[8] = {h0[0], h0[1], h0[2], h0[3], h1[0], h1[1], h1[2], h1[3]};
    float hn[8];
#pragma unroll
    for (int i = 0; i < 8; ++i) {
      float z = sigf(zs[i]), r = sigf(rs[i]);
      float cand = tanhfast(ih[i] + r * hh[i]);
      hn[i] = z * hold[i] + (1.f - z) * cand;
    }
    unsigned int qa = 0, qb = 0;
#pragma unroll
    for (int i = 0; i < 4; ++i) {
      qa |= ((unsigned int)((int)rintf(hn[i] * 127.f) & 0xff)) << (8 * i);
      qb |= ((unsigned int)((int)rintf(hn[4 + i] * 127.f) & 0xff)) << (8 * i);
    }
    *reinterpret_cast<f32x4*>(H0F + idx)     = f32x4{hn[0], hn[1], hn[2], hn[3]};
    *reinterpret_cast<f32x4*>(H0F + idx + 4) = f32x4{hn[4], hn[5], hn[6], hn[7]};
    *reinterpret_cast<uint2*>(H0Q + idx) = make_uint2(qa, qb);
  }
  if (d >= 1) {
    float iz[8] = {0,0,0,0,0,0,0,0}, ir[8] = {0,0,0,0,0,0,0,0}, ih[8] = {0,0,0,0,0,0,0,0};
    float hz[8] = {0,0,0,0,0,0,0,0}, hr[8] = {0,0,0,0,0,0,0,0}, hh[8] = {0,0,0,0,0,0,0,0};
#pragma unroll
    for (int p = 0; p < 4; ++p) {
      acc8(iz, G1I + (size_t)p * PLANE + idx);
      acc8(ir, G1I + (size_t)(4 + p) * PLANE + idx);
      acc8(ih, G1I + (size_t)(8 + p) * PLANE + idx);
      acc8(hz, G1R + (size_t)p * PLANE + idx);
      acc8(hr, G1R + (size_t)(4 + p) * PLANE + idx);
      acc8(hh, G1R + (size_t)(8 + p) * PLANE + idx);
    }
    addbias8(iz, b1 + u);           addbias8(hz, b1 + G3 + u);
    addbias8(ir, b1 + UU + u);      addbias8(hr, b1 + G3 + UU + u);
    addbias8(ih, b1 + 2 * UU + u);  addbias8(hh, b1 + G3 + 2 * UU + u);
    f32x4 h0 = *reinterpret_cast<const f32x4*>(H1F + idx);
    f32x4 h1 = *reinterpret_cast<const f32x4*>(H1F + idx + 4);
    float hold[8] = {h0[0], h0[1], h0[2], h0[3], h1[0], h1[1], h1[2], h1[3]};
    float hn[8];
#pragma unroll
    for (int i = 0; i < 8; ++i) {
      float z = sigf(iz[i] + hz[i]), r = sigf(ir[i] + hr[i]);
      float cand = tanhfast(ih[i] + r * hh[i]);
      hn[i] = z * hold[i] + (1.f - z) * cand;
    }
    unsigned int qa = 0, qb = 0;
#pragma unroll
    for (int i = 0; i < 4; ++i) {
      qa |= ((unsigned int)((int)rintf(hn[i] * 127.f) & 0xff)) << (8 * i);
      qb |= ((unsigned int)((int)rintf(hn[4 + i] * 127.f) & 0xff)) << (8 * i);
    }
    *reinterpret_cast<f32x4*>(H1F + idx)     = f32x4{hn[0], hn[1], hn[2], hn[3]};
    *reinterpret_cast<f32x4*>(H1F + idx + 4) = f32x4{hn[4], hn[5], hn[6], hn[7]};
    *reinterpret_cast<uint2*>(H1Q + idx) = make_uint2(qa, qb);
  }
}

// logits = sigmoid(h1 @ wout + bout): 128 blocks x 64 threads, one row each.
__global__ void out_k(const float* __restrict__ h1, const float* __restrict__ wout,
                      const float* __restrict__ bout, float* __restrict__ out) {
  int row = blockIdx.x;
  int lane = threadIdx.x;
  float s = 0.f;
  for (int i = lane; i < UU; i += 64) s += h1[(size_t)row * UU + i] * wout[i];
#pragma unroll
  for (int off = 32; off > 0; off >>= 1) s += __shfl_down(s, off);
  if (lane == 0) out[row] = 1.f / (1.f + __expf(-(s + bout[0])));
}

extern "C" void kernel_launch(void* const* d_in, const int* in_sizes, int n_in,
                              void* d_out, int out_size, void* d_ws, size_t ws_size,
                              hipStream_t stream) {
  const int*   tokens = (const int*)  d_in[0];
  const float* emb    = (const float*)d_in[1];
  const float* k0     = (const float*)d_in[2];
  const float* r0     = (const float*)d_in[3];
  const float* b0     = (const float*)d_in[4];
  const float* k1     = (const float*)d_in[5];
  const float* r1     = (const float*)d_in[6];
  const float* b1     = (const float*)d_in[7];
  const float* wout   = (const float*)d_in[8];
  const float* bout   = (const float*)d_in[9];
  float* out = (float*)d_out;

  char* ws = (char*)d_ws;
  unsigned short* W0K = (unsigned short*)(ws + 0);           //  1.5 MB bf16 tiled
  signed char* QW0R   = (signed char*)(ws + 1572864);        // 12.6 MB int8 tiled
  signed char* QW1K   = (signed char*)(ws + 14155776);       // 12.6 MB
  signed char* QW1R   = (signed char*)(ws + 26738688);       // 12.6 MB
  float* FS0R         = (float*)(ws + 39321600);             // 24 KB dequant scales
  float* FS1K         = (float*)(ws + 39346176);
  float* FS1R         = (float*)(ws + 39370752);
  float* QI0R         = (float*)(ws + 39395328);             // 24 KB quant inv-scales
  float* QI1K         = (float*)(ws + 39419904);
  float* QI1R         = (float*)(ws + 39444480);
  unsigned short* X   = (unsigned short*)(ws + 39469056);    //  2.6 MB bf16
  float* H0F          = (float*)(ws + 42090496);             //  1 MB fp32 state
  float* H1F          = (float*)(ws + 43139072);             //  1 MB
  signed char* H0Q    = (signed char*)(ws + 44187648);       //  0.25 MB int8 state
  signed char* H1Q    = (signed char*)(ws + 44449792);       //  0.25 MB
  unsigned short* G0  = (unsigned short*)(ws + 44711936);    // 13 bf16 planes (6.5 MB)
  unsigned short* G1I = (unsigned short*)(ws + 51527680);    // 12 bf16 planes (6 MB)
  unsigned short* G1R = (unsigned short*)(ws + 57819136);    // 12 bf16 planes (6 MB)
  // total ws use: 64,110,592 bytes

  // zero h state (H0F, H1F, H0Q, H1Q contiguous): 2.5 MiB
  hipMemsetAsync(ws + 42090496, 0, 2621440, stream);
  // zero colmax accumulators (QI0R/QI1K/QI1R contiguous, 3 x 24 KB)
  hipMemsetAsync(ws + 39395328, 0, 73728, stream);

  // per-column absmax: fused two-stage reduction at full occupancy
  // (2304 blocks, float4 coalesced, atomicMax on uint bits), then finalize.
  colmax_k<<<2304, 256, 0, stream>>>(r0, k1, r1, (unsigned int*)QI0R);
  colscale_fin_k<<<72, 256, 0, stream>>>(FS0R, (unsigned int*)QI0R);

  // int8 tiled conversion, all three matrices in one launch
  convert_w_i8<<<9216, 256, 0, stream>>>(r0, k1, r1, QI0R, QW0R);

  // L0 input-proj weights stay bf16 (tiny, K=128 padded)
  convert_w<<<384, 256, 0, stream>>>(k0, W0K, 100, 2);

  // embedding gather (time-major, padded)
  embed_k<<<5120, 256, 0, stream>>>(tokens, emb, X);

  // 81 pipelined step dispatches: d computes h0(d) and h1(d-1) concurrently
  for (int d = 0; d <= TT; ++d) {
    step_gemms<<<768, 256, 0, stream>>>(d, X, W0K, QW0R, QW1K, QW1R,
                                        FS0R, FS1K, FS1R, H0Q, H1Q,
                                        G0, G1I, G1R);
    gates_k<<<256, 128, 0, stream>>>(d, G0, G1I, G1R, b0, b1,
                                     H0F, H0Q, H1F, H1Q);
  }

  out_k<<<128, 64, 0, stream>>>(H1F, wout, bout, out);
}